// Round 5
// baseline (331.624 us; speedup 1.0000x reference)
//
#include <hip/hip_runtime.h>
#include <stdint.h>

typedef unsigned short u16;
typedef __attribute__((ext_vector_type(8))) short bf16x8;
typedef __attribute__((ext_vector_type(4))) float f32x4;
typedef __attribute__((ext_vector_type(16))) float f32x16;
typedef __attribute__((ext_vector_type(4))) uint32_t u32x4;
typedef __attribute__((ext_vector_type(2))) int int2v;

#define T_LEN 2048
#define D_DIM 1024
#define H_DIM 128
// sqrt(128) * log2(e)
#define SCALE_LOG2 16.32223116f

#define EXP2F(x) __builtin_amdgcn_exp2f(x)

__device__ __forceinline__ u16 f2bf(float f) {
  uint32_t u = __float_as_uint(f);
  u += 0x7FFFu + ((u >> 16) & 1u);
  return (u16)(u >> 16);
}
__device__ __forceinline__ float bf2f(u16 h) { return __uint_as_float(((uint32_t)h) << 16); }

__device__ __forceinline__ void gload16(const void* g, void* l) {
  __builtin_amdgcn_global_load_lds(
      (const __attribute__((address_space(1))) uint32_t*)(uintptr_t)g,
      (__attribute__((address_space(3))) uint32_t*)(uint32_t)(uintptr_t)l,
      16, 0, 0);
}

#define VMCNT0() asm volatile("s_waitcnt vmcnt(0)" ::: "memory")
#define VMLG0() asm volatile("s_waitcnt vmcnt(0) lgkmcnt(0)" ::: "memory")
#define LGKM0() asm volatile("s_waitcnt lgkmcnt(0)" ::: "memory")
#define BAR() __builtin_amdgcn_s_barrier()
#define PRIO(n) __builtin_amdgcn_s_setprio(n)

#define MFMA(a, b, c) __builtin_amdgcn_mfma_f32_16x16x32_bf16((a), (b), (c), 0, 0, 0)
#define MFMA32(a, b, c) __builtin_amdgcn_mfma_f32_32x32x16_bf16((a), (b), (c), 0, 0, 0)

// pack two f32 -> bf16x2 word (low = first arg)
__device__ __forceinline__ uint32_t cvtpk(float lo, float hi) {
  uint32_t r;
  asm("v_cvt_pk_bf16_f32 %0, %1, %2" : "=v"(r) : "v"(lo), "v"(hi));
  return r;
}
// a' = {a.lo32lanes, b.lo32lanes->hi}, b' = {a.hi32lanes->lo, b.hi32lanes}
__device__ __forceinline__ void plswap(uint32_t& a, uint32_t& b, int hi) {
#if __has_builtin(__builtin_amdgcn_permlane32_swap)
  int2v r = __builtin_amdgcn_permlane32_swap((int)a, (int)b, false, false);
  a = (uint32_t)r.x;
  b = (uint32_t)r.y;
#else
  uint32_t as = (uint32_t)__shfl_xor((int)a, 32);
  uint32_t bs = (uint32_t)__shfl_xor((int)b, 32);
  uint32_t na = hi ? bs : a;
  uint32_t nb = hi ? b : as;
  a = na;
  b = nb;
#endif
}

// ---------------------------------------------------------------------------
// Kernel 0: split W matrices into bf16 hi/lo planes, transposed to wT[h][d].
// ---------------------------------------------------------------------------
__global__ __launch_bounds__(256) void prep_w(
    const float* __restrict__ Wk, const float* __restrict__ Wq, const float* __restrict__ Wv,
    u16* __restrict__ wqh, u16* __restrict__ wql,
    u16* __restrict__ wkh, u16* __restrict__ wkl,
    u16* __restrict__ wvh) {
  __shared__ u16 th[3][128][16];
  __shared__ u16 tl[2][128][16];
  const int i = threadIdx.x;
  const int d0 = blockIdx.x * 16;
  const int dl = i >> 4;
  const int hb = (i & 15) * 8;
  const int d = d0 + dl;
#pragma unroll
  for (int e = 0; e < 8; ++e) {
    int h = hb + e;
    float q = Wq[d * H_DIM + h] * SCALE_LOG2;
    float k = Wk[d * H_DIM + h];
    float v = Wv[d * H_DIM + h];
    u16 qh = f2bf(q); th[0][h][dl] = qh; tl[0][h][dl] = f2bf(q - bf2f(qh));
    u16 kh = f2bf(k); th[1][h][dl] = kh; tl[1][h][dl] = f2bf(k - bf2f(kh));
    th[2][h][dl] = f2bf(v);
  }
  __syncthreads();
  const int h = i >> 1, c = i & 1;
  u16* planes[5] = {wqh, wql, wkh, wkl, wvh};
  const u16* srcs[5] = {&th[0][0][0], &tl[0][0][0], &th[1][0][0], &tl[1][0][0], &th[2][0][0]};
#pragma unroll
  for (int p = 0; p < 5; ++p) {
    bf16x8 v8 = *(const bf16x8*)(srcs[p] + h * 16 + c * 8);
    *(bf16x8*)(planes[p] + h * 1024 + d0 + c * 8) = v8;
  }
}

// ---------------------------------------------------------------------------
// Kernel 1: QKV projection. 512 threads / 8 waves (2 waves/SIMD), 64 rows,
// 2-phase prefetch pipeline (double-buffered LDS). Wave w owns h-tile w.
// (unchanged from round 4 — known-good)
// ---------------------------------------------------------------------------
#define QBUF 53248  // 52 KB per buffer: A(12K) + W(40K)

__global__ __launch_bounds__(512) void qkv_proj(
    const float* __restrict__ att, const float* __restrict__ x,
    const u16* __restrict__ wqh, const u16* __restrict__ wql,
    const u16* __restrict__ wkh, const u16* __restrict__ wkl,
    const u16* __restrict__ wvh,
    const float* __restrict__ bq, const float* __restrict__ bk, const float* __restrict__ bv,
    u16* __restrict__ qhp, u16* __restrict__ qlp,
    u16* __restrict__ khp, u16* __restrict__ klp,
    u16* __restrict__ vtp) {
  __shared__ __attribute__((aligned(128))) char lds[104 * 1024];

  const int tid = threadIdx.x;
  const int wid = tid >> 6;
  const int ln = tid & 63;
  const int g = ln >> 4;
  const int cl = ln & 15;
  const int t0g = blockIdx.x * 64;

  const f32x4 fz = {0.f, 0.f, 0.f, 0.f};
  f32x4 accq[4], acck[4], accv[4];
#pragma unroll
  for (int s = 0; s < 4; ++s) { accq[s] = fz; acck[s] = fz; accv[s] = fz; }

  const int isA = tid < 256;
  const int at = tid & 255;
  const int arow = at >> 2;
  const int ac = at & 3;
  const float* srcp = (isA ? att : x) + (size_t)(t0g + arow) * D_DIM + ac * 8;
  const int aw_off = (isA ? 0 : 8192) + arow * 64 + ((ac ^ ((arow >> 1) & 3)) * 16);

  auto STAGE_W = [&](int b, int ks) {
    char* wt = lds + b * QBUF + 12288;
#pragma unroll
    for (int j = 0; j < 5; ++j) {
      int seg = wid * 5 + j;
      int p = seg >> 3;
      int s = seg & 7;
      int db = s * 1024 + ln * 16;
      int row = db >> 6;
      int c = (db >> 4) & 3;
      int cs = c ^ ((row >> 1) & 3);
      const u16* wp = (p == 0) ? wqh : (p == 1) ? wql : (p == 2) ? wkh : (p == 3) ? wkl : wvh;
      gload16(wp + row * 1024 + ks * 32 + cs * 8, wt + p * 8192 + s * 1024);
    }
  };
  auto CWRITE_A = [&](int b, f32x4 f0, f32x4 f1) {
    bf16x8 vh, vl;
#pragma unroll
    for (int e = 0; e < 4; ++e) {
      u16 h0 = f2bf(f0[e]); vh[e] = (short)h0; vl[e] = (short)f2bf(f0[e] - bf2f(h0));
      u16 h1 = f2bf(f1[e]); vh[e + 4] = (short)h1; vl[e + 4] = (short)f2bf(f1[e] - bf2f(h1));
    }
    char* dst = lds + b * QBUF + aw_off;
    *(bf16x8*)dst = vh;
    if (isA) *(bf16x8*)(dst + 4096) = vl;
  };

  {
    f32x4 f0 = *(const f32x4*)(srcp);
    f32x4 f1 = *(const f32x4*)(srcp + 4);
    STAGE_W(0, 0);
    CWRITE_A(0, f0, f1);
  }
  VMLG0();
  BAR();

  int cur = 0;
  for (int ks = 0; ks < 32; ++ks) {
    f32x4 pf0, pf1;
    if (ks < 31) {
      pf0 = *(const f32x4*)(srcp + (ks + 1) * 32);
      pf1 = *(const f32x4*)(srcp + (ks + 1) * 32 + 4);
      STAGE_W(cur ^ 1, ks + 1);
    }
    char* base = lds + cur * QBUF;
    char* wt = base + 12288;
    bf16x8 ah[4], al[4], xh[4];
#pragma unroll
    for (int s = 0; s < 4; ++s) {
      int row = s * 16 + cl;
      int byte = row * 64 + ((g ^ ((row >> 1) & 3)) * 16);
      ah[s] = *(const bf16x8*)(base + byte);
      al[s] = *(const bf16x8*)(base + 4096 + byte);
      xh[s] = *(const bf16x8*)(base + 8192 + byte);
    }
    {
      int hrow = wid * 16 + cl;
      int wb = hrow * 64 + ((g ^ ((hrow >> 1) & 3)) * 16);
      bf16x8 bqh_ = *(const bf16x8*)(wt + 0 * 8192 + wb);
      bf16x8 bql_ = *(const bf16x8*)(wt + 1 * 8192 + wb);
      bf16x8 bkh_ = *(const bf16x8*)(wt + 2 * 8192 + wb);
      bf16x8 bkl_ = *(const bf16x8*)(wt + 3 * 8192 + wb);
      bf16x8 bvh_ = *(const bf16x8*)(wt + 4 * 8192 + wb);
      PRIO(1);
#pragma unroll
      for (int s = 0; s < 4; ++s) {
        accq[s] = MFMA(ah[s], bqh_, accq[s]);
        accq[s] = MFMA(al[s], bqh_, accq[s]);
        accq[s] = MFMA(ah[s], bql_, accq[s]);
        acck[s] = MFMA(ah[s], bkh_, acck[s]);
        acck[s] = MFMA(al[s], bkh_, acck[s]);
        acck[s] = MFMA(ah[s], bkl_, acck[s]);
        accv[s] = MFMA(xh[s], bvh_, accv[s]);
      }
      PRIO(0);
    }
    if (ks < 31) CWRITE_A(cur ^ 1, pf0, pf1);
    VMLG0();
    BAR();
    cur ^= 1;
  }

  char* vbuf = lds;
  {
    int h = wid * 16 + cl;
    float bqv = bq[h] * SCALE_LOG2, bkv = bk[h], bvv = bv[h];
#pragma unroll
    for (int s = 0; s < 4; ++s) {
#pragma unroll
      for (int r = 0; r < 4; ++r) {
        int t = s * 16 + g * 4 + r;
        size_t idx = (size_t)(t0g + t) * H_DIM + h;
        float qv = accq[s][r] + bqv;
        u16 qh_ = f2bf(qv);
        qhp[idx] = qh_;
        qlp[idx] = f2bf(qv - bf2f(qh_));
        float kv = acck[s][r] + bkv;
        u16 kh_ = f2bf(kv);
        khp[idx] = kh_;
        klp[idx] = f2bf(kv - bf2f(kh_));
        float vv = accv[s][r] + bvv;
        int c3 = t >> 3;
        int byte = h * 128 + ((c3 ^ (h & 7)) * 16) + (t & 7) * 2;
        *(u16*)(vbuf + byte) = f2bf(vv);
      }
    }
  }
  __syncthreads();
  {
    int h = tid >> 2, qtr = tid & 3;
    int b2 = t0g >> 11;
    int tb = t0g & 2047;
    u16* dst = vtp + ((size_t)(b2 * H_DIM + h)) * T_LEN + tb + qtr * 16;
#pragma unroll
    for (int c2 = 0; c2 < 2; ++c2) {
      int c3 = qtr * 2 + c2;
      bf16x8 v8 = *(const bf16x8*)(vbuf + h * 128 + ((c3 ^ (h & 7)) * 16));
      *(bf16x8*)(dst + c2 * 8) = v8;
    }
  }
}

// ---------------------------------------------------------------------------
// Kernel 2: flash attention, swapped-QK^T (S[kpos][q]) with in-register
// softmax. 4 waves: (qtile 0/1) x (kv-half 0/1). KVB=32. K hi/lo staged to
// LDS (reg-staged, issue-early/write-late); V read direct (L2-resident).
// P never touches LDS: cvt_pk + permlane32_swap builds PV A-frags in regs.
// Defer-max rescaling (THR=8, log2 domain). Split-KV LDS merge at end.
// ---------------------------------------------------------------------------
#define NTILES 32

__global__ __launch_bounds__(256, 1) void attn(
    const u16* __restrict__ qhp, const u16* __restrict__ qlp,
    const u16* __restrict__ khp, const u16* __restrict__ klp,
    const u16* __restrict__ vtp,
    float* __restrict__ out) {
  // main phase: [kvh][plane][32 rows][16 slots][16B] = 32 KB; ml @32768
  // merge phase (after sync): partner O 2x16KB @0, ml @32768
  __shared__ __attribute__((aligned(128))) char lds[33 * 1024];

  const int tid = threadIdx.x;
  const int w = tid >> 6;
  const int l = tid & 63;
  const int q5 = l & 31;     // q index within tile (and kpos-row for K frags)
  const int hi = l >> 5;
  const int bid = blockIdx.x;
  const int b_ = bid & 7;    // batch -> XCD locality
  const int t0 = (bid >> 3) * 64;
  const int wq = w >> 1;     // q-tile within block
  const int kvh = w & 1;     // kv half
  const int qrow = t0 + wq * 32 + q5;
  const int tkb = kvh * 1024;

  // ---- Q fragments (hi/lo) in registers ----
  bf16x8 qh[8], ql[8];
  {
    const u16* qb = qhp + ((size_t)(b_ * T_LEN + qrow)) * H_DIM + hi * 8;
    const u16* qlb = qlp + ((size_t)(b_ * T_LEN + qrow)) * H_DIM + hi * 8;
#pragma unroll
    for (int kc = 0; kc < 8; ++kc) {
      qh[kc] = *(const bf16x8*)(qb + kc * 16);
      ql[kc] = *(const bf16x8*)(qlb + kc * 16);
    }
  }

  // ---- staging decode (8 granules/thread, both halves, both K planes) ----
  uint32_t goff[8], ldsoff[8];
#pragma unroll
  for (int i = 0; i < 8; ++i) {
    int gid = i * 256 + tid;      // 0..2047
    int half = gid >> 10;
    int plane = (gid >> 9) & 1;
    int n = gid & 511;
    int row = n >> 4;
    int slot = n & 15;
    int dg = slot ^ (row & 15);   // XOR-swizzle (granule within 256B row)
    goff[i] = (uint32_t)(plane * 2097152 +
                         (b_ * T_LEN + half * 1024 + row) * H_DIM + dg * 8);
    ldsoff[i] = (uint32_t)(gid * 16);
  }

  f32x16 o[4] = {};
  float m_ = -1e30f;
  float l_ = 0.f;

  // ---- prologue: stage tile 0 ----
  int4 st[8];
#pragma unroll
  for (int i = 0; i < 8; ++i) st[i] = *(const int4*)(khp + goff[i]);
#pragma unroll
  for (int i = 0; i < 8; ++i) *(int4*)(lds + ldsoff[i]) = st[i];
  __syncthreads();

  for (int t = 0; t < NTILES; ++t) {
    // issue next-tile K loads early (land during compute)
    if (t < NTILES - 1) {
#pragma unroll
      for (int i = 0; i < 8; ++i)
        st[i] = *(const int4*)(khp + goff[i] + (t + 1) * 4096);
    }
    // V B-frags direct from global (L1/L2-resident region), issued early
    bf16x8 vfr[8];
#pragma unroll
    for (int ks = 0; ks < 2; ++ks)
#pragma unroll
      for (int nt = 0; nt < 4; ++nt)
        vfr[ks * 4 + nt] = *(const bf16x8*)(
            vtp + ((size_t)(b_ * H_DIM + nt * 32 + q5)) * T_LEN +
            tkb + t * 32 + ks * 16 + hi * 8);

    // ---- QK^T: S[kpos=q5-row][q], split hi/lo ----
    f32x16 s = {};
#pragma unroll
    for (int kc = 0; kc < 8; ++kc) {
      int slot = (kc * 2 + hi) ^ (q5 & 15);
      const char* kb = lds + kvh * 16384 + q5 * 256 + slot * 16;
      bf16x8 kh_f = *(const bf16x8*)(kb);
      bf16x8 kl_f = *(const bf16x8*)(kb + 8192);
      s = MFMA32(kh_f, qh[kc], s);
      s = MFMA32(kl_f, qh[kc], s);
      s = MFMA32(kh_f, ql[kc], s);
    }

    // ---- in-register online softmax (exp2 domain) ----
    float pmax = s[0];
#pragma unroll
    for (int j = 1; j < 16; ++j) pmax = fmaxf(pmax, s[j]);
    pmax = fmaxf(pmax, __shfl_xor(pmax, 32));
    if (__any(pmax > m_ + 8.f)) {
      float mn = fmaxf(m_, pmax);
      float sf = EXP2F(m_ - mn);
      m_ = mn;
      l_ *= sf;
#pragma unroll
      for (int j = 0; j < 16; ++j) {
        int rj = (j & 3) + 8 * (j >> 2) + 4 * hi;
        float sfj = __shfl(sf, rj);
        o[0][j] *= sfj; o[1][j] *= sfj; o[2][j] *= sfj; o[3][j] *= sfj;
      }
    }
    float p[16];
#pragma unroll
    for (int j = 0; j < 16; ++j) p[j] = EXP2F(s[j] - m_);
    float ps = 0.f;
#pragma unroll
    for (int j = 0; j < 16; ++j) ps += p[j];
    ps += __shfl_xor(ps, 32);
    l_ += ps;

    // ---- P -> bf16 A-frags (registers only) ----
    uint32_t u0 = cvtpk(p[0], p[1]), v0 = cvtpk(p[4], p[5]);
    uint32_t u1 = cvtpk(p[2], p[3]), v1 = cvtpk(p[6], p[7]);
    uint32_t u2 = cvtpk(p[8], p[9]), v2 = cvtpk(p[12], p[13]);
    uint32_t u3 = cvtpk(p[10], p[11]), v3 = cvtpk(p[14], p[15]);
    plswap(u0, v0, hi);
    plswap(u1, v1, hi);
    plswap(u2, v2, hi);
    plswap(u3, v3, hi);
    u32x4 f0w = {u0, u1, v0, v1};
    u32x4 f1w = {u2, u3, v2, v3};
    bf16x8 pa0 = *(bf16x8*)&f0w;
    bf16x8 pa1 = *(bf16x8*)&f1w;

    // ---- PV ----
#pragma unroll
    for (int nt = 0; nt < 4; ++nt) o[nt] = MFMA32(pa0, vfr[nt], o[nt]);
#pragma unroll
    for (int nt = 0; nt < 4; ++nt) o[nt] = MFMA32(pa1, vfr[4 + nt], o[nt]);

    // ---- tile handoff: write prefetched K (loads have landed by now) ----
    LGKM0();
    BAR();
    if (t < NTILES - 1) {
#pragma unroll
      for (int i = 0; i < 8; ++i) *(int4*)(lds + ldsoff[i]) = st[i];
    }
    LGKM0();
    BAR();
  }

  // ---- split-KV merge: kvh=1 publishes (O, m, l); kvh=0 combines+stores ----
  __syncthreads();
  if (kvh == 1) {
    float* ob = (float*)(lds + wq * 16384);
#pragma unroll
    for (int nt = 0; nt < 4; ++nt)
#pragma unroll
      for (int j = 0; j < 16; ++j) ob[nt * 1024 + j * 64 + l] = o[nt][j];
    if (hi == 0) {
      float* mlb = (float*)(lds + 32768 + wq * 256);
      mlb[q5 * 2] = m_;
      mlb[q5 * 2 + 1] = l_;
    }
  }
  __syncthreads();
  if (kvh == 0) {
    float* ob = (float*)(lds + wq * 16384);
    float* mlb = (float*)(lds + 32768 + wq * 256);
    float mB = mlb[q5 * 2], lB = mlb[q5 * 2 + 1];
    float mM = fmaxf(m_, mB);
    float fa = EXP2F(m_ - mM), fb = EXP2F(mB - mM);
    float inv = 1.f / (l_ * fa + lB * fb);
    float sA = fa * inv, sB = fb * inv;
#pragma unroll
    for (int j = 0; j < 16; ++j) {
      int rj = (j & 3) + 8 * (j >> 2) + 4 * hi;
      float sAj = __shfl(sA, rj);
      float sBj = __shfl(sB, rj);
      size_t rbase = ((size_t)(b_ * T_LEN + t0 + wq * 32 + rj)) * H_DIM + q5;
#pragma unroll
      for (int nt = 0; nt < 4; ++nt) {
        out[rbase + nt * 32] = o[nt][j] * sAj + ob[nt * 1024 + j * 64 + l] * sBj;
      }
    }
  }
}

// ---------------------------------------------------------------------------
extern "C" void kernel_launch(void* const* d_in, const int* in_sizes, int n_in,
                              void* d_out, int out_size, void* d_ws, size_t ws_size,
                              hipStream_t stream) {
  const float* x   = (const float*)d_in[0];
  const float* att = (const float*)d_in[1];
  const float* Wk  = (const float*)d_in[2];
  const float* bk  = (const float*)d_in[3];
  const float* Wq  = (const float*)d_in[4];
  const float* bq  = (const float*)d_in[5];
  const float* Wv  = (const float*)d_in[6];
  const float* bv  = (const float*)d_in[7];
  float* out = (float*)d_out;
  char* ws = (char*)d_ws;

  u16* wqh = (u16*)(ws);
  u16* wql = (u16*)(ws + 256 * 1024);
  u16* wkh = (u16*)(ws + 512 * 1024);
  u16* wkl = (u16*)(ws + 768 * 1024);
  u16* wvh = (u16*)(ws + 1024 * 1024);
  u16* qhp = (u16*)(ws + (size_t)2 * 1024 * 1024);
  u16* qlp = (u16*)(ws + (size_t)6 * 1024 * 1024);
  u16* khp = (u16*)(ws + (size_t)10 * 1024 * 1024);
  u16* klp = (u16*)(ws + (size_t)14 * 1024 * 1024);  // khp + 2097152 elems
  u16* vtp = (u16*)(ws + (size_t)18 * 1024 * 1024);

  prep_w<<<64, 256, 0, stream>>>(Wk, Wq, Wv, wqh, wql, wkh, wkl, wvh);
  qkv_proj<<<256, 512, 0, stream>>>(att, x, wqh, wql, wkh, wkl, wvh,
                                    bq, bk, bv, qhp, qlp, khp, klp, vtp);
  attn<<<256, 256, 0, stream>>>(qhp, qlp, khp, klp, vtp, out);
}

// Round 6
// 264.048 us; speedup vs baseline: 1.2559x; 1.2559x over previous
//
#include <hip/hip_runtime.h>
#include <stdint.h>

typedef unsigned short u16;
typedef __attribute__((ext_vector_type(8))) short bf16x8;
typedef __attribute__((ext_vector_type(4))) float f32x4;
typedef __attribute__((ext_vector_type(16))) float f32x16;
typedef __attribute__((ext_vector_type(4))) uint32_t u32x4;
typedef __attribute__((ext_vector_type(2))) int int2v;

#define T_LEN 2048
#define D_DIM 1024
#define H_DIM 128
// sqrt(128) * log2(e)
#define SCALE_LOG2 16.32223116f

#define EXP2F(x) __builtin_amdgcn_exp2f(x)

__device__ __forceinline__ u16 f2bf(float f) {
  uint32_t u = __float_as_uint(f);
  u += 0x7FFFu + ((u >> 16) & 1u);
  return (u16)(u >> 16);
}
__device__ __forceinline__ float bf2f(u16 h) { return __uint_as_float(((uint32_t)h) << 16); }

__device__ __forceinline__ void gload16(const void* g, void* l) {
  __builtin_amdgcn_global_load_lds(
      (const __attribute__((address_space(1))) uint32_t*)(uintptr_t)g,
      (__attribute__((address_space(3))) uint32_t*)(uint32_t)(uintptr_t)l,
      16, 0, 0);
}

#define VMCNT0() asm volatile("s_waitcnt vmcnt(0)" ::: "memory")
#define VMLG0() asm volatile("s_waitcnt vmcnt(0) lgkmcnt(0)" ::: "memory")
#define BAR() __builtin_amdgcn_s_barrier()
#define PRIO(n) __builtin_amdgcn_s_setprio(n)

#define MFMA(a, b, c) __builtin_amdgcn_mfma_f32_16x16x32_bf16((a), (b), (c), 0, 0, 0)
#define MFMA32(a, b, c) __builtin_amdgcn_mfma_f32_32x32x16_bf16((a), (b), (c), 0, 0, 0)

// pack two f32 -> bf16x2 word (low = first arg)
__device__ __forceinline__ uint32_t cvtpk(float lo, float hi) {
  uint32_t r;
  asm("v_cvt_pk_bf16_f32 %0, %1, %2" : "=v"(r) : "v"(lo), "v"(hi));
  return r;
}
__device__ __forceinline__ void plswap(uint32_t& a, uint32_t& b, int hi) {
#if __has_builtin(__builtin_amdgcn_permlane32_swap)
  int2v r = __builtin_amdgcn_permlane32_swap((int)a, (int)b, false, false);
  a = (uint32_t)r.x;
  b = (uint32_t)r.y;
#else
  uint32_t as = (uint32_t)__shfl_xor((int)a, 32);
  uint32_t bs = (uint32_t)__shfl_xor((int)b, 32);
  uint32_t na = hi ? bs : a;
  uint32_t nb = hi ? b : as;
  a = na;
  b = nb;
#endif
}

// ---------------------------------------------------------------------------
// Kernel 0: split W matrices into bf16 hi/lo planes, transposed to wT[h][d].
// ---------------------------------------------------------------------------
__global__ __launch_bounds__(256) void prep_w(
    const float* __restrict__ Wk, const float* __restrict__ Wq, const float* __restrict__ Wv,
    u16* __restrict__ wqh, u16* __restrict__ wql,
    u16* __restrict__ wkh, u16* __restrict__ wkl,
    u16* __restrict__ wvh) {
  __shared__ u16 th[3][128][16];
  __shared__ u16 tl[2][128][16];
  const int i = threadIdx.x;
  const int d0 = blockIdx.x * 16;
  const int dl = i >> 4;
  const int hb = (i & 15) * 8;
  const int d = d0 + dl;
#pragma unroll
  for (int e = 0; e < 8; ++e) {
    int h = hb + e;
    float q = Wq[d * H_DIM + h] * SCALE_LOG2;
    float k = Wk[d * H_DIM + h];
    float v = Wv[d * H_DIM + h];
    u16 qh = f2bf(q); th[0][h][dl] = qh; tl[0][h][dl] = f2bf(q - bf2f(qh));
    u16 kh = f2bf(k); th[1][h][dl] = kh; tl[1][h][dl] = f2bf(k - bf2f(kh));
    th[2][h][dl] = f2bf(v);
  }
  __syncthreads();
  const int h = i >> 1, c = i & 1;
  u16* planes[5] = {wqh, wql, wkh, wkl, wvh};
  const u16* srcs[5] = {&th[0][0][0], &tl[0][0][0], &th[1][0][0], &tl[1][0][0], &th[2][0][0]};
#pragma unroll
  for (int p = 0; p < 5; ++p) {
    bf16x8 v8 = *(const bf16x8*)(srcs[p] + h * 16 + c * 8);
    *(bf16x8*)(planes[p] + h * 1024 + d0 + c * 8) = v8;
  }
}

// ---------------------------------------------------------------------------
// Kernel 1: QKV projection. 512 threads / 8 waves (2 waves/SIMD), 64 rows,
// 2-phase W prefetch + 2-DEEP A prefetch (covers ~900cy HBM latency).
// ---------------------------------------------------------------------------
#define QBUF 53248  // 52 KB per buffer: A(12K) + W(40K)

__global__ __launch_bounds__(512) void qkv_proj(
    const float* __restrict__ att, const float* __restrict__ x,
    const u16* __restrict__ wqh, const u16* __restrict__ wql,
    const u16* __restrict__ wkh, const u16* __restrict__ wkl,
    const u16* __restrict__ wvh,
    const float* __restrict__ bq, const float* __restrict__ bk, const float* __restrict__ bv,
    u16* __restrict__ qhp, u16* __restrict__ qlp,
    u16* __restrict__ khp, u16* __restrict__ klp,
    u16* __restrict__ vtp) {
  __shared__ __attribute__((aligned(128))) char lds[104 * 1024];

  const int tid = threadIdx.x;
  const int wid = tid >> 6;
  const int ln = tid & 63;
  const int g = ln >> 4;
  const int cl = ln & 15;
  const int t0g = blockIdx.x * 64;

  const f32x4 fz = {0.f, 0.f, 0.f, 0.f};
  f32x4 accq[4], acck[4], accv[4];
#pragma unroll
  for (int s = 0; s < 4; ++s) { accq[s] = fz; acck[s] = fz; accv[s] = fz; }

  const int isA = tid < 256;
  const int at = tid & 255;
  const int arow = at >> 2;
  const int ac = at & 3;
  const float* srcp = (isA ? att : x) + (size_t)(t0g + arow) * D_DIM + ac * 8;
  const int aw_off = (isA ? 0 : 8192) + arow * 64 + ((ac ^ ((arow >> 1) & 3)) * 16);

  auto STAGE_W = [&](int b, int ks) {
    char* wt = lds + b * QBUF + 12288;
#pragma unroll
    for (int j = 0; j < 5; ++j) {
      int seg = wid * 5 + j;
      int p = seg >> 3;
      int s = seg & 7;
      int db = s * 1024 + ln * 16;
      int row = db >> 6;
      int c = (db >> 4) & 3;
      int cs = c ^ ((row >> 1) & 3);
      const u16* wp = (p == 0) ? wqh : (p == 1) ? wql : (p == 2) ? wkh : (p == 3) ? wkl : wvh;
      gload16(wp + row * 1024 + ks * 32 + cs * 8, wt + p * 8192 + s * 1024);
    }
  };
  auto CWRITE_A = [&](int b, f32x4 f0, f32x4 f1) {
    bf16x8 vh, vl;
#pragma unroll
    for (int e = 0; e < 4; ++e) {
      u16 h0 = f2bf(f0[e]); vh[e] = (short)h0; vl[e] = (short)f2bf(f0[e] - bf2f(h0));
      u16 h1 = f2bf(f1[e]); vh[e + 4] = (short)h1; vl[e + 4] = (short)f2bf(f1[e] - bf2f(h1));
    }
    char* dst = lds + b * QBUF + aw_off;
    *(bf16x8*)dst = vh;
    if (isA) *(bf16x8*)(dst + 4096) = vl;
  };

  // --- prologue: fill buffer 0 for ks=0; prefetch A(1) into regs ---
  {
    f32x4 f0 = *(const f32x4*)(srcp);
    f32x4 f1 = *(const f32x4*)(srcp + 4);
    STAGE_W(0, 0);
    CWRITE_A(0, f0, f1);
  }
  f32x4 pA0 = *(const f32x4*)(srcp + 32);
  f32x4 pA1 = *(const f32x4*)(srcp + 36);
  VMLG0();
  BAR();

  int cur = 0;
  for (int ks = 0; ks < 32; ++ks) {
    // --- issue A(ks+2) loads + W(ks+1) stages early ---
    f32x4 nA0, nA1;
    if (ks < 30) {
      nA0 = *(const f32x4*)(srcp + (ks + 2) * 32);
      nA1 = *(const f32x4*)(srcp + (ks + 2) * 32 + 4);
    }
    if (ks < 31) STAGE_W(cur ^ 1, ks + 1);
    // --- compute on current buffer ---
    char* base = lds + cur * QBUF;
    char* wt = base + 12288;
    bf16x8 ah[4], al[4], xh[4];
#pragma unroll
    for (int s = 0; s < 4; ++s) {
      int row = s * 16 + cl;
      int byte = row * 64 + ((g ^ ((row >> 1) & 3)) * 16);
      ah[s] = *(const bf16x8*)(base + byte);
      al[s] = *(const bf16x8*)(base + 4096 + byte);
      xh[s] = *(const bf16x8*)(base + 8192 + byte);
    }
    {
      int hrow = wid * 16 + cl;
      int wb = hrow * 64 + ((g ^ ((hrow >> 1) & 3)) * 16);
      bf16x8 bqh_ = *(const bf16x8*)(wt + 0 * 8192 + wb);
      bf16x8 bql_ = *(const bf16x8*)(wt + 1 * 8192 + wb);
      bf16x8 bkh_ = *(const bf16x8*)(wt + 2 * 8192 + wb);
      bf16x8 bkl_ = *(const bf16x8*)(wt + 3 * 8192 + wb);
      bf16x8 bvh_ = *(const bf16x8*)(wt + 4 * 8192 + wb);
      PRIO(1);
#pragma unroll
      for (int s = 0; s < 4; ++s) {
        accq[s] = MFMA(ah[s], bqh_, accq[s]);
        accq[s] = MFMA(al[s], bqh_, accq[s]);
        accq[s] = MFMA(ah[s], bql_, accq[s]);
        acck[s] = MFMA(ah[s], bkh_, acck[s]);
        acck[s] = MFMA(al[s], bkh_, acck[s]);
        acck[s] = MFMA(ah[s], bkl_, acck[s]);
        accv[s] = MFMA(xh[s], bvh_, accv[s]);
      }
      PRIO(0);
    }
    // --- write A(ks+1), loaded a full step ago ---
    if (ks < 31) CWRITE_A(cur ^ 1, pA0, pA1);
    pA0 = nA0;
    pA1 = nA1;
    VMLG0();
    BAR();
    cur ^= 1;
  }

  char* vbuf = lds;
  {
    int h = wid * 16 + cl;
    float bqv = bq[h] * SCALE_LOG2, bkv = bk[h], bvv = bv[h];
#pragma unroll
    for (int s = 0; s < 4; ++s) {
#pragma unroll
      for (int r = 0; r < 4; ++r) {
        int t = s * 16 + g * 4 + r;
        size_t idx = (size_t)(t0g + t) * H_DIM + h;
        float qv = accq[s][r] + bqv;
        u16 qh_ = f2bf(qv);
        qhp[idx] = qh_;
        qlp[idx] = f2bf(qv - bf2f(qh_));
        float kv = acck[s][r] + bkv;
        u16 kh_ = f2bf(kv);
        khp[idx] = kh_;
        klp[idx] = f2bf(kv - bf2f(kh_));
        float vv = accv[s][r] + bvv;
        int c3 = t >> 3;
        int byte = h * 128 + ((c3 ^ (h & 7)) * 16) + (t & 7) * 2;
        *(u16*)(vbuf + byte) = f2bf(vv);
      }
    }
  }
  __syncthreads();
  {
    int h = tid >> 2, qtr = tid & 3;
    int b2 = t0g >> 11;
    int tb = t0g & 2047;
    u16* dst = vtp + ((size_t)(b2 * H_DIM + h)) * T_LEN + tb + qtr * 16;
#pragma unroll
    for (int c2 = 0; c2 < 2; ++c2) {
      int c3 = qtr * 2 + c2;
      bf16x8 v8 = *(const bf16x8*)(vbuf + h * 128 + ((c3 ^ (h & 7)) * 16));
      *(bf16x8*)(dst + c2 * 8) = v8;
    }
  }
}

// ---------------------------------------------------------------------------
// Kernel 2: flash attention. 512 threads / 8 waves = 2 q-tiles x 4 kv-quarters
// (2 waves/SIMD). Swapped QK^T (S[kpos][q]) via MFMA32, 3 score accumulators,
// in-register softmax (cvt_pk + permlane32_swap), defer-max THR=8.
// K hi/lo per quarter staged in LDS via global_load_lds (pre-swizzled source,
// double-buffered, 1 barrier/tile). V read direct from L2. 4-way LDS merge.
// ---------------------------------------------------------------------------
#define KVB 32
#define NT 16  // tiles per quarter (512 kv / 32)

__global__ __launch_bounds__(512, 2) void attn(
    const u16* __restrict__ qhp, const u16* __restrict__ qlp,
    const u16* __restrict__ khp, const u16* __restrict__ klp,
    const u16* __restrict__ vtp,
    float* __restrict__ out) {
  // [quarter][dbuf] 16KB each = 128KB; merge reuses [0,96K) + ml @96K
  __shared__ __attribute__((aligned(128))) char lds[128 * 1024];

  const int tid = threadIdx.x;
  const int w = tid >> 6;
  const int l = tid & 63;
  const int q5 = l & 31;
  const int hi = l >> 5;
  const int wq = w >> 2;        // q-tile 0/1
  const int kvq = w & 3;        // kv quarter
  const int pi = wq;            // index within staging pair
  const int bid = blockIdx.x;
  const int b_ = bid & 7;       // batch -> XCD
  const int t0 = (bid >> 3) * 64;
  const int qrow = t0 + wq * 32 + q5;
  const int kv0q = kvq * 512;

  // ---- Q fragments (hi/lo) in registers ----
  bf16x8 qh[8], ql[8];
  {
    const u16* qb = qhp + (size_t)(b_ * T_LEN + qrow) * H_DIM + hi * 8;
    const u16* qlb = qlp + (size_t)(b_ * T_LEN + qrow) * H_DIM + hi * 8;
#pragma unroll
    for (int kc = 0; kc < 8; ++kc) {
      qh[kc] = *(const bf16x8*)(qb + kc * 16);
      ql[kc] = *(const bf16x8*)(qlb + kc * 16);
    }
  }

  // ---- staging decode: 8 gload16 per wave, pair covers 16KB tile ----
  // LDS linear: [plane(1)][row(5)][slot(4)] x 16B; source granule pre-swizzled
  uint32_t sgoff[8];
#pragma unroll
  for (int i = 0; i < 8; ++i) {
    int gid = i * 128 + pi * 64 + l;  // 0..1023
    int plane = gid >> 9;
    int n = gid & 511;
    int row = n >> 4;
    int slot = n & 15;
    int dg = slot ^ (row & 15);
    sgoff[i] = (uint32_t)(plane * 2097152 + (b_ * T_LEN + row) * H_DIM + dg * 8);
  }
  char* const qbuf0 = lds + kvq * 2 * 16384;

  auto STAGE = [&](int b, int kvoff) {
    char* buf = qbuf0 + b * 16384;
#pragma unroll
    for (int i = 0; i < 8; ++i)
      gload16(khp + sgoff[i] + (uint32_t)(kvoff * H_DIM), buf + i * 2048 + pi * 1024);
  };

  f32x16 o[4] = {};
  float m_ = -1e30f;
  float l_ = 0.f;

  STAGE(0, kv0q);
  VMCNT0();
  BAR();

  int cur = 0;
  for (int t = 0; t < NT; ++t) {
    if (t < NT - 1) STAGE(cur ^ 1, kv0q + (t + 1) * KVB);
    // V B-frags direct from global (L2-resident), issued early
    bf16x8 vfr[8];
#pragma unroll
    for (int ks = 0; ks < 2; ++ks)
#pragma unroll
      for (int nt = 0; nt < 4; ++nt)
        vfr[ks * 4 + nt] = *(const bf16x8*)(
            vtp + (size_t)(b_ * H_DIM + nt * 32 + q5) * T_LEN +
            kv0q + t * KVB + ks * 16 + hi * 8);

    // ---- QK^T: 3 accumulators (no dependent-MFMA stalls) ----
    const char* kb = qbuf0 + cur * 16384 + q5 * 256;
    f32x16 s0 = {}, s1 = {}, s2 = {};
    PRIO(1);
#pragma unroll
    for (int kc = 0; kc < 8; ++kc) {
      int slot = (((kc * 2 + hi) ^ (q5 & 15)) * 16);
      bf16x8 kh_f = *(const bf16x8*)(kb + slot);
      bf16x8 kl_f = *(const bf16x8*)(kb + 8192 + slot);
      s0 = MFMA32(kh_f, qh[kc], s0);
      s1 = MFMA32(kl_f, qh[kc], s1);
      s2 = MFMA32(kh_f, ql[kc], s2);
    }
    PRIO(0);
    f32x16 s = (s0 + s1) + s2;

    // ---- in-register online softmax (exp2 domain), defer-max THR=8 ----
    float pmax = s[0];
#pragma unroll
    for (int j = 1; j < 16; ++j) pmax = fmaxf(pmax, s[j]);
    pmax = fmaxf(pmax, __shfl_xor(pmax, 32));
    if (__any(pmax > m_ + 8.f)) {
      float mn = fmaxf(m_, pmax);
      float sf = EXP2F(m_ - mn);
      m_ = mn;
      l_ *= sf;
#pragma unroll
      for (int j = 0; j < 16; ++j) {
        int rj = (j & 3) + 8 * (j >> 2) + 4 * hi;
        float sfj = __shfl(sf, rj);
        o[0][j] *= sfj; o[1][j] *= sfj; o[2][j] *= sfj; o[3][j] *= sfj;
      }
    }
    float p[16];
#pragma unroll
    for (int j = 0; j < 16; ++j) p[j] = EXP2F(s[j] - m_);
    float ps = 0.f;
#pragma unroll
    for (int j = 0; j < 16; ++j) ps += p[j];
    ps += __shfl_xor(ps, 32);
    l_ += ps;

    // ---- P -> bf16 A-frags (registers only) ----
    uint32_t u0 = cvtpk(p[0], p[1]), v0 = cvtpk(p[4], p[5]);
    uint32_t u1 = cvtpk(p[2], p[3]), v1 = cvtpk(p[6], p[7]);
    uint32_t u2 = cvtpk(p[8], p[9]), v2 = cvtpk(p[12], p[13]);
    uint32_t u3 = cvtpk(p[10], p[11]), v3 = cvtpk(p[14], p[15]);
    plswap(u0, v0, hi);
    plswap(u1, v1, hi);
    plswap(u2, v2, hi);
    plswap(u3, v3, hi);
    u32x4 f0w = {u0, u1, v0, v1};
    u32x4 f1w = {u2, u3, v2, v3};
    bf16x8 pa0 = *(bf16x8*)&f0w;
    bf16x8 pa1 = *(bf16x8*)&f1w;

    // ---- PV ----
    PRIO(1);
#pragma unroll
    for (int nt = 0; nt < 4; ++nt) o[nt] = MFMA32(pa0, vfr[nt], o[nt]);
#pragma unroll
    for (int nt = 0; nt < 4; ++nt) o[nt] = MFMA32(pa1, vfr[4 + nt], o[nt]);
    PRIO(0);

    VMCNT0();
    BAR();
    cur ^= 1;
  }

  // ---- 4-way split-KV merge ----
  float* mlb = (float*)(lds + 96 * 1024);
  __syncthreads();
  if (hi == 0) {
    mlb[(wq * 4 + kvq) * 64 + q5 * 2] = m_;
    mlb[(wq * 4 + kvq) * 64 + q5 * 2 + 1] = l_;
  }
  __syncthreads();
  // each wave computes its own normalized scale for its q-rows
  float sc;
  {
    float ms0 = mlb[(wq * 4 + 0) * 64 + q5 * 2], ls0 = mlb[(wq * 4 + 0) * 64 + q5 * 2 + 1];
    float ms1 = mlb[(wq * 4 + 1) * 64 + q5 * 2], ls1 = mlb[(wq * 4 + 1) * 64 + q5 * 2 + 1];
    float ms2 = mlb[(wq * 4 + 2) * 64 + q5 * 2], ls2 = mlb[(wq * 4 + 2) * 64 + q5 * 2 + 1];
    float ms3 = mlb[(wq * 4 + 3) * 64 + q5 * 2], ls3 = mlb[(wq * 4 + 3) * 64 + q5 * 2 + 1];
    float mM = fmaxf(fmaxf(ms0, ms1), fmaxf(ms2, ms3));
    float L = ls0 * EXP2F(ms0 - mM) + ls1 * EXP2F(ms1 - mM) +
              ls2 * EXP2F(ms2 - mM) + ls3 * EXP2F(ms3 - mM);
    sc = EXP2F(m_ - mM) / L;
  }
#pragma unroll
  for (int j = 0; j < 16; ++j) {
    int rj = (j & 3) + 8 * (j >> 2) + 4 * hi;
    float scj = __shfl(sc, rj);
    o[0][j] *= scj; o[1][j] *= scj; o[2][j] *= scj; o[3][j] *= scj;
  }
  if (kvq != 0) {
    float* ob = (float*)(lds + (wq * 3 + (kvq - 1)) * 16384);
#pragma unroll
    for (int nt = 0; nt < 4; ++nt)
#pragma unroll
      for (int j = 0; j < 16; ++j) ob[nt * 1024 + j * 64 + l] = o[nt][j];
  }
  __syncthreads();
  if (kvq == 0) {
    float* ob0 = (float*)(lds + (wq * 3 + 0) * 16384);
    float* ob1 = (float*)(lds + (wq * 3 + 1) * 16384);
    float* ob2 = (float*)(lds + (wq * 3 + 2) * 16384);
#pragma unroll
    for (int j = 0; j < 16; ++j) {
      int rj = (j & 3) + 8 * (j >> 2) + 4 * hi;
      size_t rbase = (size_t)(b_ * T_LEN + t0 + wq * 32 + rj) * H_DIM + q5;
#pragma unroll
      for (int nt = 0; nt < 4; ++nt) {
        int oi = nt * 1024 + j * 64 + l;
        out[rbase + nt * 32] = o[nt][j] + ob0[oi] + ob1[oi] + ob2[oi];
      }
    }
  }
}

// ---------------------------------------------------------------------------
extern "C" void kernel_launch(void* const* d_in, const int* in_sizes, int n_in,
                              void* d_out, int out_size, void* d_ws, size_t ws_size,
                              hipStream_t stream) {
  const float* x   = (const float*)d_in[0];
  const float* att = (const float*)d_in[1];
  const float* Wk  = (const float*)d_in[2];
  const float* bk  = (const float*)d_in[3];
  const float* Wq  = (const float*)d_in[4];
  const float* bq  = (const float*)d_in[5];
  const float* Wv  = (const float*)d_in[6];
  const float* bv  = (const float*)d_in[7];
  float* out = (float*)d_out;
  char* ws = (char*)d_ws;

  u16* wqh = (u16*)(ws);
  u16* wql = (u16*)(ws + 256 * 1024);
  u16* wkh = (u16*)(ws + 512 * 1024);
  u16* wkl = (u16*)(ws + 768 * 1024);
  u16* wvh = (u16*)(ws + 1024 * 1024);
  u16* qhp = (u16*)(ws + (size_t)2 * 1024 * 1024);
  u16* qlp = (u16*)(ws + (size_t)6 * 1024 * 1024);
  u16* khp = (u16*)(ws + (size_t)10 * 1024 * 1024);
  u16* klp = (u16*)(ws + (size_t)14 * 1024 * 1024);  // khp + 2097152 elems
  u16* vtp = (u16*)(ws + (size_t)18 * 1024 * 1024);

  prep_w<<<64, 256, 0, stream>>>(Wk, Wq, Wv, wqh, wql, wkh, wkl, wvh);
  qkv_proj<<<256, 512, 0, stream>>>(att, x, wqh, wql, wkh, wkl, wvh,
                                    bq, bk, bv, qhp, qlp, khp, klp, vtp);
  attn<<<256, 512, 0, stream>>>(qhp, qlp, khp, klp, vtp, out);
}